// Round 1
// baseline (170.906 us; speedup 1.0000x reference)
//
#include <hip/hip_runtime.h>
#include <hip/hip_bf16.h>
#include <stdint.h>

// MultiHeadCrossAttention: B=8, C=512, H=W=32 (S=1024), nh=8, d=64.
// Pipeline: transpose+bf16-cast -> 3x projection GEMM (MFMA bf16) -> fused flash attention.
// All MFMA operands arranged K-fast (gemm_bt pattern) so fragments are ds/global_read_b128-able.

typedef __attribute__((ext_vector_type(4))) float f32x4;
typedef __attribute__((ext_vector_type(8))) short short8;

#define GLB_AS(p) ((const __attribute__((address_space(1))) void*)(p))
#define LDS_AS(p) ((__attribute__((address_space(3))) void*)(p))

__device__ __forceinline__ unsigned short f2b(float f) {
  unsigned int x = __builtin_bit_cast(unsigned int, f);
  x = (x + 0x7FFFu + ((x >> 16) & 1u)) >> 16;   // RNE
  return (unsigned short)x;
}

__device__ __forceinline__ f32x4 mfma16(short8 a, short8 b, f32x4 c) {
  return __builtin_amdgcn_mfma_f32_16x16x32_bf16(a, b, c, 0, 0, 0);
}

// ---- prep: X[b, c(512), s(1024)] f32  ->  Xt[b, s(1024), c(512)] bf16 ----
__global__ __launch_bounds__(256) void transpose_cast(const float* __restrict__ X,
                                                      unsigned short* __restrict__ Xt) {
  __shared__ float t[64][65];
  const int s0 = blockIdx.x * 64, c0 = blockIdx.y * 64;
  const float* Xb = X + (long)blockIdx.z * 512 * 1024;
  const int tid = threadIdx.x;
  const int col4 = (tid & 15) * 4;
  const int r0 = tid >> 4;
#pragma unroll
  for (int it = 0; it < 4; ++it) {
    int r = r0 + it * 16;
    const float4 v = *(const float4*)&Xb[(long)(c0 + r) * 1024 + s0 + col4];
    t[r][col4 + 0] = v.x; t[r][col4 + 1] = v.y; t[r][col4 + 2] = v.z; t[r][col4 + 3] = v.w;
  }
  __syncthreads();
  const int s = tid >> 2;
  const int cp = (tid & 3) * 16;
  unsigned int u[8];
#pragma unroll
  for (int i = 0; i < 8; ++i) {
    unsigned int lo = f2b(t[cp + 2 * i][s]);
    unsigned int hi = f2b(t[cp + 2 * i + 1][s]);
    u[i] = lo | (hi << 16);
  }
  unsigned short* dst = Xt + ((long)blockIdx.z * 1024 + s0 + s) * 512 + c0 + cp;
  ((uint4*)dst)[0] = make_uint4(u[0], u[1], u[2], u[3]);
  ((uint4*)dst)[1] = make_uint4(u[4], u[5], u[6], u[7]);
}

// ---- prep: weight f32 -> bf16 flat ----
__global__ __launch_bounds__(256) void cast_w(const float* __restrict__ W,
                                              unsigned short* __restrict__ O, int n4) {
  int i = blockIdx.x * 256 + threadIdx.x;
  if (i >= n4) return;
  float4 v = ((const float4*)W)[i];
  uint2 u;
  u.x = (unsigned)f2b(v.x) | ((unsigned)f2b(v.y) << 16);
  u.y = (unsigned)f2b(v.z) | ((unsigned)f2b(v.w) << 16);
  ((uint2*)O)[i] = u;
}

// ---- projection GEMM: C[m,n] = scale * ( sum_k A[m,k]*B[n,k] + bias )  (all bf16, f32 acc)
// A row-major [M,K] K-fast, B row-major [N,K] K-fast, C row-major [M,N] bf16.
// 128x128 tile, BK=64, 4 waves (each 64x64 = 4x4 16x16 frags), global_load_lds width 16.
__global__ __launch_bounds__(256, 2) void gemm_bt(
    const unsigned short* __restrict__ A, const unsigned short* __restrict__ B,
    unsigned short* __restrict__ C, const float* __restrict__ bias,
    int M, int N, int K, long aBS, long bBS, long cBS, float scale, int biasN) {
  __shared__ __align__(16) unsigned short lA[128 * 64];
  __shared__ __align__(16) unsigned short lB[128 * 64];
  const unsigned short* Ab = A + (long)blockIdx.z * aBS;
  const unsigned short* Bb = B + (long)blockIdx.z * bBS;
  unsigned short* Cb = C + (long)blockIdx.z * cBS;
  const int m0 = blockIdx.y * 128, n0 = blockIdx.x * 128;
  const int tid = threadIdx.x, lane = tid & 63, wid = tid >> 6;
  const int wr = wid >> 1, wc = wid & 1;
  const int lm = lane & 15, lg = lane >> 4;
  f32x4 acc[4][4] = {};
  for (int k0 = 0; k0 < K; k0 += 64) {
    // stage A and B tiles: LDS linear [128][64] bf16; each wave moves 4 KiB per tile
#pragma unroll
    for (int ch = wid; ch < 16; ch += 4) {
      int e = ch * 512 + lane * 8;
      int r = e >> 6, cc = e & 63;
      __builtin_amdgcn_global_load_lds(GLB_AS(Ab + (long)(m0 + r) * K + k0 + cc),
                                       LDS_AS(lA + ch * 512), 16, 0, 0);
      __builtin_amdgcn_global_load_lds(GLB_AS(Bb + (long)(n0 + r) * K + k0 + cc),
                                       LDS_AS(lB + ch * 512), 16, 0, 0);
    }
    __syncthreads();
#pragma unroll
    for (int kk = 0; kk < 2; ++kk) {
      short8 af[4], bf[4];
#pragma unroll
      for (int i = 0; i < 4; ++i)
        af[i] = *(const short8*)&lA[(wr * 64 + i * 16 + lm) * 64 + kk * 32 + 8 * lg];
#pragma unroll
      for (int j = 0; j < 4; ++j)
        bf[j] = *(const short8*)&lB[(wc * 64 + j * 16 + lm) * 64 + kk * 32 + 8 * lg];
#pragma unroll
      for (int i = 0; i < 4; ++i)
#pragma unroll
        for (int j = 0; j < 4; ++j)
          acc[i][j] = mfma16(af[i], bf[j], acc[i][j]);
    }
    __syncthreads();
  }
  // epilogue: C/D layout col=lane&15, row=(lane>>4)*4+r (learn_hip-verified)
#pragma unroll
  for (int i = 0; i < 4; ++i)
#pragma unroll
    for (int j = 0; j < 4; ++j)
#pragma unroll
      for (int r = 0; r < 4; ++r) {
        int m = m0 + wr * 64 + i * 16 + lg * 4 + r;
        int n = n0 + wc * 64 + j * 16 + lm;
        float bv = biasN ? bias[n] : bias[m];
        Cb[(long)m * N + n] = f2b((acc[i][j][r] + bv) * scale);
      }
}

// ---- fused flash attention ----
// Qt[b,s,c], Kt[b,s,c] bf16 (c fast, Q pre-scaled by 1/8); V[b,c,t] bf16 (t fast).
// grid (8 s-tiles, 8 heads, 8 batch), 4 independent waves x 32 s-rows. No barriers.
__global__ __launch_bounds__(256, 2) void attn(
    const unsigned short* __restrict__ Qt, const unsigned short* __restrict__ Kt,
    const unsigned short* __restrict__ V, float* __restrict__ Out) {
  __shared__ __align__(16) unsigned short Pl[4][32][72];  // pad 72: 144B rows, 16B-aligned
  const int st = blockIdx.x, h = blockIdx.y, b = blockIdx.z;
  const int tid = threadIdx.x, lane = tid & 63, w = tid >> 6;
  const int lm = lane & 15, lg = lane >> 4;
  const int s0 = st * 128 + w * 32;
  const unsigned short* Qb = Qt + ((long)b * 1024 + s0) * 512 + h * 64;
  const unsigned short* Kb = Kt + (long)b * 1024 * 512 + h * 64;
  const unsigned short* Vb = V + ((long)b * 512 + h * 64) * 1024;

  short8 qf[2][2];
#pragma unroll
  for (int si = 0; si < 2; ++si)
#pragma unroll
    for (int kk = 0; kk < 2; ++kk)
      qf[si][kk] = *(const short8*)&Qb[(si * 16 + lm) * 512 + kk * 32 + 8 * lg];

  f32x4 o[2][4] = {};
  float mrun[2][4], lrun[2][4];
#pragma unroll
  for (int si = 0; si < 2; ++si)
#pragma unroll
    for (int r = 0; r < 4; ++r) { mrun[si][r] = -1e30f; lrun[si][r] = 0.f; }

  for (int t0 = 0; t0 < 1024; t0 += 64) {
    // QK^T: S[s,t] fragments (A=Q rows, B=Kt rows, both K-fast over d)
    f32x4 s[2][4] = {};
#pragma unroll
    for (int tj = 0; tj < 4; ++tj) {
      short8 kf0 = *(const short8*)&Kb[(long)(t0 + tj * 16 + lm) * 512 + 8 * lg];
      short8 kf1 = *(const short8*)&Kb[(long)(t0 + tj * 16 + lm) * 512 + 32 + 8 * lg];
#pragma unroll
      for (int si = 0; si < 2; ++si) {
        s[si][tj] = mfma16(qf[si][0], kf0, s[si][tj]);
        s[si][tj] = mfma16(qf[si][1], kf1, s[si][tj]);
      }
    }
    // online softmax: row stats live in lanes sharing lg; reduce over 16 col-lanes
#pragma unroll
    for (int si = 0; si < 2; ++si)
#pragma unroll
      for (int r = 0; r < 4; ++r) {
        float tm = fmaxf(fmaxf(s[si][0][r], s[si][1][r]), fmaxf(s[si][2][r], s[si][3][r]));
        tm = fmaxf(tm, __shfl_xor(tm, 1));
        tm = fmaxf(tm, __shfl_xor(tm, 2));
        tm = fmaxf(tm, __shfl_xor(tm, 4));
        tm = fmaxf(tm, __shfl_xor(tm, 8));
        float mnew = fmaxf(mrun[si][r], tm);
        float sc = __expf(mrun[si][r] - mnew);
        mrun[si][r] = mnew;
        float rs = 0.f;
#pragma unroll
        for (int tj = 0; tj < 4; ++tj) {
          float p = __expf(s[si][tj][r] - mnew);
          s[si][tj][r] = p;
          rs += p;
        }
        rs += __shfl_xor(rs, 1);
        rs += __shfl_xor(rs, 2);
        rs += __shfl_xor(rs, 4);
        rs += __shfl_xor(rs, 8);
        lrun[si][r] = lrun[si][r] * sc + rs;
#pragma unroll
        for (int dj = 0; dj < 4; ++dj) o[si][dj][r] *= sc;
      }
    // P: C-layout -> LDS -> A-layout (per-wave private tile, no barrier needed)
#pragma unroll
    for (int si = 0; si < 2; ++si)
#pragma unroll
      for (int tj = 0; tj < 4; ++tj)
#pragma unroll
        for (int r = 0; r < 4; ++r)
          Pl[w][si * 16 + lg * 4 + r][tj * 16 + lm] = f2b(s[si][tj][r]);
    // PV: A=P rows (t-fast), B=V^T rows (t-fast), accumulate O
#pragma unroll
    for (int tk = 0; tk < 2; ++tk) {
      short8 pa0 = *(const short8*)&Pl[w][lm][tk * 32 + 8 * lg];
      short8 pa1 = *(const short8*)&Pl[w][16 + lm][tk * 32 + 8 * lg];
#pragma unroll
      for (int dj = 0; dj < 4; ++dj) {
        short8 vf = *(const short8*)&Vb[(long)(dj * 16 + lm) * 1024 + t0 + tk * 32 + 8 * lg];
        o[0][dj] = mfma16(pa0, vf, o[0][dj]);
        o[1][dj] = mfma16(pa1, vf, o[1][dj]);
      }
    }
  }
  // epilogue: out[b, s, h*64+dd] (torch-faithful reshape => [B,S,C] memory order)
  float inv[2][4];
#pragma unroll
  for (int si = 0; si < 2; ++si)
#pragma unroll
    for (int r = 0; r < 4; ++r) inv[si][r] = 1.0f / lrun[si][r];
#pragma unroll
  for (int si = 0; si < 2; ++si)
#pragma unroll
    for (int dj = 0; dj < 4; ++dj)
#pragma unroll
      for (int r = 0; r < 4; ++r) {
        int srow = s0 + si * 16 + lg * 4 + r;
        Out[((long)b * 1024 + srow) * 512 + h * 64 + dj * 16 + lm] = o[si][dj][r] * inv[si][r];
      }
}

extern "C" void kernel_launch(void* const* d_in, const int* in_sizes, int n_in,
                              void* d_out, int out_size, void* d_ws, size_t ws_size,
                              hipStream_t stream) {
  const float* query = (const float*)d_in[0];
  const float* key   = (const float*)d_in[1];
  const float* value = (const float*)d_in[2];
  const float* wq = (const float*)d_in[3];
  const float* bq = (const float*)d_in[4];
  const float* wk = (const float*)d_in[5];
  const float* bk = (const float*)d_in[6];
  const float* wv = (const float*)d_in[7];
  const float* bv = (const float*)d_in[8];

  unsigned short* ws = (unsigned short*)d_ws;
  const long SC = 1024L * 512;  // per-batch matrix elems
  unsigned short* XTQ = ws;                       // 8*SC
  unsigned short* XTK = XTQ + 8 * SC;
  unsigned short* XTV = XTK + 8 * SC;
  unsigned short* WQ  = XTV + 8 * SC;             // 512*512 each
  unsigned short* WK  = WQ + 512 * 512;
  unsigned short* WV  = WK + 512 * 512;
  unsigned short* QT  = WV + 512 * 512;           // 8*SC each
  unsigned short* KTm = QT + 8 * SC;
  unsigned short* VVm = KTm + 8 * SC;             // total ~51 MB of d_ws

  dim3 tg(16, 8, 8);
  transpose_cast<<<tg, 256, 0, stream>>>(query, XTQ);
  transpose_cast<<<tg, 256, 0, stream>>>(key, XTK);
  transpose_cast<<<tg, 256, 0, stream>>>(value, XTV);
  cast_w<<<256, 256, 0, stream>>>(wq, WQ, 65536);
  cast_w<<<256, 256, 0, stream>>>(wk, WK, 65536);
  cast_w<<<256, 256, 0, stream>>>(wv, WV, 65536);
  // Qt[s,c] = (Xt_q . Wq^T + bq) * 1/sqrt(64);  Kt[s,c] = Xt_k . Wk^T + bk
  gemm_bt<<<dim3(4, 8, 8), 256, 0, stream>>>(XTQ, WQ, QT, bq, 1024, 512, 512, SC, 0, SC, 0.125f, 1);
  gemm_bt<<<dim3(4, 8, 8), 256, 0, stream>>>(XTK, WK, KTm, bk, 1024, 512, 512, SC, 0, SC, 1.0f, 1);
  // V[c,t] = Wv . Xt_v^T + bv (bias over rows)
  gemm_bt<<<dim3(8, 4, 8), 256, 0, stream>>>(WV, XTV, VVm, bv, 512, 1024, 512, 0, SC, SC, 1.0f, 0);
  attn<<<dim3(8, 8, 8), 256, 0, stream>>>(QT, KTm, VVm, (float*)d_out);
}

// Round 3
// 116.200 us; speedup vs baseline: 1.4708x; 1.4708x over previous
//
#include <hip/hip_runtime.h>
#include <hip/hip_bf16.h>
#include <stdint.h>

// MultiHeadCrossAttention: B=8, C=512, H=W=32 (S=1024), nh=8, d=64.
// R2 == R1 resubmit (R2 bench was an infra failure, no signal):
// attn register-prefetch (V early + K double-buffered), setprio around MFMA,
// merged prep launches (10 -> 5 dispatches).

typedef __attribute__((ext_vector_type(4))) float f32x4;
typedef __attribute__((ext_vector_type(8))) short short8;

#define GLB_AS(p) ((const __attribute__((address_space(1))) void*)(p))
#define LDS_AS(p) ((__attribute__((address_space(3))) void*)(p))

__device__ __forceinline__ unsigned short f2b(float f) {
  unsigned int x = __builtin_bit_cast(unsigned int, f);
  x = (x + 0x7FFFu + ((x >> 16) & 1u)) >> 16;   // RNE
  return (unsigned short)x;
}

__device__ __forceinline__ f32x4 mfma16(short8 a, short8 b, f32x4 c) {
  return __builtin_amdgcn_mfma_f32_16x16x32_bf16(a, b, c, 0, 0, 0);
}

// ---- prep: X[b, c(512), s(1024)] f32 -> Xt[b, s(1024), c(512)] bf16, 3 tensors in one ----
__global__ __launch_bounds__(256) void transpose_cast3(const float* __restrict__ Xq,
                                                       const float* __restrict__ Xk,
                                                       const float* __restrict__ Xv,
                                                       unsigned short* __restrict__ Xt) {
  __shared__ float t[64][65];
  const int which = blockIdx.z >> 3, bb = blockIdx.z & 7;
  const float* X = (which == 0) ? Xq : ((which == 1) ? Xk : Xv);
  const int s0 = blockIdx.x * 64, c0 = blockIdx.y * 64;
  const float* Xb = X + (long)bb * 512 * 1024;
  const int tid = threadIdx.x;
  const int col4 = (tid & 15) * 4;
  const int r0 = tid >> 4;
#pragma unroll
  for (int it = 0; it < 4; ++it) {
    int r = r0 + it * 16;
    const float4 v = *(const float4*)&Xb[(long)(c0 + r) * 1024 + s0 + col4];
    t[r][col4 + 0] = v.x; t[r][col4 + 1] = v.y; t[r][col4 + 2] = v.z; t[r][col4 + 3] = v.w;
  }
  __syncthreads();
  const int s = tid >> 2;
  const int cp = (tid & 3) * 16;
  unsigned int u[8];
#pragma unroll
  for (int i = 0; i < 8; ++i) {
    unsigned int lo = f2b(t[cp + 2 * i][s]);
    unsigned int hi = f2b(t[cp + 2 * i + 1][s]);
    u[i] = lo | (hi << 16);
  }
  unsigned short* dst = Xt + (long)which * 8 * 1024 * 512 +
                        ((long)bb * 1024 + s0 + s) * 512 + c0 + cp;
  ((uint4*)dst)[0] = make_uint4(u[0], u[1], u[2], u[3]);
  ((uint4*)dst)[1] = make_uint4(u[4], u[5], u[6], u[7]);
}

// ---- prep: 3 weights f32 -> bf16, one launch ----
__global__ __launch_bounds__(256) void cast_w3(const float* __restrict__ wq,
                                               const float* __restrict__ wk,
                                               const float* __restrict__ wv,
                                               unsigned short* __restrict__ O) {
  const int y = blockIdx.y;
  const float* W = (y == 0) ? wq : ((y == 1) ? wk : wv);
  int i = blockIdx.x * 256 + threadIdx.x;   // 65536 float4 per weight
  float4 v = ((const float4*)W)[i];
  uint2 u;
  u.x = (unsigned)f2b(v.x) | ((unsigned)f2b(v.y) << 16);
  u.y = (unsigned)f2b(v.z) | ((unsigned)f2b(v.w) << 16);
  ((uint2*)(O + (long)y * 262144))[i] = u;
}

// ---- merged Q+K projection GEMM: z in [0,16): z<8 -> Q (scale 1/8, bias bq), else K ----
// A = Xt [z][1024,512] K-fast; Bw = W [512,512] K-fast; C[z][1024,512] bf16.
__global__ __launch_bounds__(256, 2) void gemm_qk(
    const unsigned short* __restrict__ A, const unsigned short* __restrict__ Bw0,
    unsigned short* __restrict__ C, const float* __restrict__ bq,
    const float* __restrict__ bk) {
  __shared__ __align__(16) unsigned short lA[128 * 64];
  __shared__ __align__(16) unsigned short lB[128 * 64];
  const int z = blockIdx.z;
  const unsigned short* Ab = A + (long)z * 1024 * 512;
  const unsigned short* Bb = Bw0 + (long)(z >> 3) * 262144;
  unsigned short* Cb = C + (long)z * 1024 * 512;
  const float* bias = (z >> 3) ? bk : bq;
  const float scale = (z >> 3) ? 1.0f : 0.125f;
  const int m0 = blockIdx.y * 128, n0 = blockIdx.x * 128;
  const int tid = threadIdx.x, lane = tid & 63, wid = tid >> 6;
  const int wr = wid >> 1, wc = wid & 1;
  const int lm = lane & 15, lg = lane >> 4;
  f32x4 acc[4][4] = {};
  for (int k0 = 0; k0 < 512; k0 += 64) {
#pragma unroll
    for (int ch = wid; ch < 16; ch += 4) {
      int e = ch * 512 + lane * 8;
      int r = e >> 6, cc = e & 63;
      __builtin_amdgcn_global_load_lds(GLB_AS(Ab + (long)(m0 + r) * 512 + k0 + cc),
                                       LDS_AS(lA + ch * 512), 16, 0, 0);
      __builtin_amdgcn_global_load_lds(GLB_AS(Bb + (long)(n0 + r) * 512 + k0 + cc),
                                       LDS_AS(lB + ch * 512), 16, 0, 0);
    }
    __syncthreads();
#pragma unroll
    for (int kk = 0; kk < 2; ++kk) {
      short8 af[4], bf[4];
#pragma unroll
      for (int i = 0; i < 4; ++i)
        af[i] = *(const short8*)&lA[(wr * 64 + i * 16 + lm) * 64 + kk * 32 + 8 * lg];
#pragma unroll
      for (int j = 0; j < 4; ++j)
        bf[j] = *(const short8*)&lB[(wc * 64 + j * 16 + lm) * 64 + kk * 32 + 8 * lg];
#pragma unroll
      for (int i = 0; i < 4; ++i)
#pragma unroll
        for (int j = 0; j < 4; ++j)
          acc[i][j] = mfma16(af[i], bf[j], acc[i][j]);
    }
    __syncthreads();
  }
#pragma unroll
  for (int i = 0; i < 4; ++i)
#pragma unroll
    for (int j = 0; j < 4; ++j)
#pragma unroll
      for (int r = 0; r < 4; ++r) {
        int m = m0 + wr * 64 + i * 16 + lg * 4 + r;
        int n = n0 + wc * 64 + j * 16 + lm;
        Cb[(long)m * 512 + n] = f2b((acc[i][j][r] + bias[n]) * scale);
      }
}

// ---- generic gemm (used for V): C[m,n] = sum_k A[m,k]B[n,k] + bias[m] ----
__global__ __launch_bounds__(256, 2) void gemm_bt(
    const unsigned short* __restrict__ A, const unsigned short* __restrict__ B,
    unsigned short* __restrict__ C, const float* __restrict__ bias,
    int M, int N, int K, long aBS, long bBS, long cBS) {
  __shared__ __align__(16) unsigned short lA[128 * 64];
  __shared__ __align__(16) unsigned short lB[128 * 64];
  const unsigned short* Ab = A + (long)blockIdx.z * aBS;
  const unsigned short* Bb = B + (long)blockIdx.z * bBS;
  unsigned short* Cb = C + (long)blockIdx.z * cBS;
  const int m0 = blockIdx.y * 128, n0 = blockIdx.x * 128;
  const int tid = threadIdx.x, lane = tid & 63, wid = tid >> 6;
  const int wr = wid >> 1, wc = wid & 1;
  const int lm = lane & 15, lg = lane >> 4;
  f32x4 acc[4][4] = {};
  for (int k0 = 0; k0 < K; k0 += 64) {
#pragma unroll
    for (int ch = wid; ch < 16; ch += 4) {
      int e = ch * 512 + lane * 8;
      int r = e >> 6, cc = e & 63;
      __builtin_amdgcn_global_load_lds(GLB_AS(Ab + (long)(m0 + r) * K + k0 + cc),
                                       LDS_AS(lA + ch * 512), 16, 0, 0);
      __builtin_amdgcn_global_load_lds(GLB_AS(Bb + (long)(n0 + r) * K + k0 + cc),
                                       LDS_AS(lB + ch * 512), 16, 0, 0);
    }
    __syncthreads();
#pragma unroll
    for (int kk = 0; kk < 2; ++kk) {
      short8 af[4], bf[4];
#pragma unroll
      for (int i = 0; i < 4; ++i)
        af[i] = *(const short8*)&lA[(wr * 64 + i * 16 + lm) * 64 + kk * 32 + 8 * lg];
#pragma unroll
      for (int j = 0; j < 4; ++j)
        bf[j] = *(const short8*)&lB[(wc * 64 + j * 16 + lm) * 64 + kk * 32 + 8 * lg];
#pragma unroll
      for (int i = 0; i < 4; ++i)
#pragma unroll
        for (int j = 0; j < 4; ++j)
          acc[i][j] = mfma16(af[i], bf[j], acc[i][j]);
    }
    __syncthreads();
  }
#pragma unroll
  for (int i = 0; i < 4; ++i)
#pragma unroll
    for (int j = 0; j < 4; ++j)
#pragma unroll
      for (int r = 0; r < 4; ++r) {
        int m = m0 + wr * 64 + i * 16 + lg * 4 + r;
        int n = n0 + wc * 64 + j * 16 + lm;
        Cb[(long)m * N + n] = f2b(acc[i][j][r] + bias[m]);
      }
}

// ---- fused flash attention with register prefetch ----
// Qt[b,s,c], Kt[b,s,c] bf16 (c fast, Q pre-scaled); V[b,c,t] bf16 (t fast).
// 4 independent waves x 32 s-rows; all global loads issued at iteration top:
// vf (this iter's V) + kn (next iter's K, double-buffered). No barriers.
__global__ __launch_bounds__(256, 2) void attn(
    const unsigned short* __restrict__ Qt, const unsigned short* __restrict__ Kt,
    const unsigned short* __restrict__ V, float* __restrict__ Out) {
  __shared__ __align__(16) unsigned short Pl[4][32][72];
  const int st = blockIdx.x, h = blockIdx.y, b = blockIdx.z;
  const int tid = threadIdx.x, lane = tid & 63, w = tid >> 6;
  const int lm = lane & 15, lg = lane >> 4;
  const int s0 = st * 128 + w * 32;
  const unsigned short* Qb = Qt + ((long)b * 1024 + s0) * 512 + h * 64;
  const unsigned short* Kb = Kt + (long)b * 1024 * 512 + h * 64;
  const unsigned short* Vb = V + ((long)b * 512 + h * 64) * 1024;

  short8 qf[2][2];
#pragma unroll
  for (int si = 0; si < 2; ++si)
#pragma unroll
    for (int kk = 0; kk < 2; ++kk)
      qf[si][kk] = *(const short8*)&Qb[(si * 16 + lm) * 512 + kk * 32 + 8 * lg];

  f32x4 o[2][4] = {};
  float mrun[2][4], lrun[2][4];
#pragma unroll
  for (int si = 0; si < 2; ++si)
#pragma unroll
    for (int r = 0; r < 4; ++r) { mrun[si][r] = -1e30f; lrun[si][r] = 0.f; }

  short8 kA[4][2], kB[4][2];
#pragma unroll
  for (int tj = 0; tj < 4; ++tj)
#pragma unroll
    for (int hh = 0; hh < 2; ++hh)
      kA[tj][hh] = *(const short8*)&Kb[(long)(tj * 16 + lm) * 512 + hh * 32 + 8 * lg];

  auto body = [&](short8 (&kc)[4][2], short8 (&kn)[4][2], int t0) {
    // issue ALL loads first: this iter's V + next iter's K stay in flight
    short8 vf[2][4];
#pragma unroll
    for (int tk = 0; tk < 2; ++tk)
#pragma unroll
      for (int dj = 0; dj < 4; ++dj)
        vf[tk][dj] = *(const short8*)&Vb[(long)(dj * 16 + lm) * 1024 + t0 + tk * 32 + 8 * lg];
    const int tn = (t0 + 64) & 1023;
#pragma unroll
    for (int tj = 0; tj < 4; ++tj)
#pragma unroll
      for (int hh = 0; hh < 2; ++hh)
        kn[tj][hh] = *(const short8*)&Kb[(long)(tn + tj * 16 + lm) * 512 + hh * 32 + 8 * lg];
    // QK^T with previously-loaded kc
    f32x4 s[2][4] = {};
    __builtin_amdgcn_s_setprio(1);
#pragma unroll
    for (int tj = 0; tj < 4; ++tj)
#pragma unroll
      for (int si = 0; si < 2; ++si) {
        s[si][tj] = mfma16(qf[si][0], kc[tj][0], s[si][tj]);
        s[si][tj] = mfma16(qf[si][1], kc[tj][1], s[si][tj]);
      }
    __builtin_amdgcn_s_setprio(0);
    // online softmax (hides vf/kn latency)
#pragma unroll
    for (int si = 0; si < 2; ++si)
#pragma unroll
      for (int r = 0; r < 4; ++r) {
        float tm = fmaxf(fmaxf(s[si][0][r], s[si][1][r]), fmaxf(s[si][2][r], s[si][3][r]));
        tm = fmaxf(tm, __shfl_xor(tm, 1));
        tm = fmaxf(tm, __shfl_xor(tm, 2));
        tm = fmaxf(tm, __shfl_xor(tm, 4));
        tm = fmaxf(tm, __shfl_xor(tm, 8));
        float mnew = fmaxf(mrun[si][r], tm);
        float sc = __expf(mrun[si][r] - mnew);
        mrun[si][r] = mnew;
        float rs = 0.f;
#pragma unroll
        for (int tj = 0; tj < 4; ++tj) {
          float p = __expf(s[si][tj][r] - mnew);
          s[si][tj][r] = p;
          rs += p;
        }
        rs += __shfl_xor(rs, 1);
        rs += __shfl_xor(rs, 2);
        rs += __shfl_xor(rs, 4);
        rs += __shfl_xor(rs, 8);
        lrun[si][r] = lrun[si][r] * sc + rs;
#pragma unroll
        for (int dj = 0; dj < 4; ++dj) o[si][dj][r] *= sc;
      }
    // P: C-layout -> LDS -> A-layout (per-wave private tile)
#pragma unroll
    for (int si = 0; si < 2; ++si)
#pragma unroll
      for (int tj = 0; tj < 4; ++tj)
#pragma unroll
        for (int r = 0; r < 4; ++r)
          Pl[w][si * 16 + lg * 4 + r][tj * 16 + lm] = f2b(s[si][tj][r]);
    // PV with prefetched vf
    __builtin_amdgcn_s_setprio(1);
#pragma unroll
    for (int tk = 0; tk < 2; ++tk) {
      short8 pa0 = *(const short8*)&Pl[w][lm][tk * 32 + 8 * lg];
      short8 pa1 = *(const short8*)&Pl[w][16 + lm][tk * 32 + 8 * lg];
#pragma unroll
      for (int dj = 0; dj < 4; ++dj) {
        o[0][dj] = mfma16(pa0, vf[tk][dj], o[0][dj]);
        o[1][dj] = mfma16(pa1, vf[tk][dj], o[1][dj]);
      }
    }
    __builtin_amdgcn_s_setprio(0);
  };
#pragma unroll 1
  for (int t0 = 0; t0 < 1024; t0 += 128) {
    body(kA, kB, t0);
    body(kB, kA, t0 + 64);
  }
  // epilogue: out[b, s, h*64+dd]
  float inv[2][4];
#pragma unroll
  for (int si = 0; si < 2; ++si)
#pragma unroll
    for (int r = 0; r < 4; ++r) inv[si][r] = 1.0f / lrun[si][r];
#pragma unroll
  for (int si = 0; si < 2; ++si)
#pragma unroll
    for (int dj = 0; dj < 4; ++dj)
#pragma unroll
      for (int r = 0; r < 4; ++r) {
        int srow = s0 + si * 16 + lg * 4 + r;
        Out[((long)b * 1024 + srow) * 512 + h * 64 + dj * 16 + lm] = o[si][dj][r] * inv[si][r];
      }
}

extern "C" void kernel_launch(void* const* d_in, const int* in_sizes, int n_in,
                              void* d_out, int out_size, void* d_ws, size_t ws_size,
                              hipStream_t stream) {
  const float* query = (const float*)d_in[0];
  const float* key   = (const float*)d_in[1];
  const float* value = (const float*)d_in[2];
  const float* wq = (const float*)d_in[3];
  const float* bq = (const float*)d_in[4];
  const float* wk = (const float*)d_in[5];
  const float* bk = (const float*)d_in[6];
  const float* wv = (const float*)d_in[7];
  const float* bv = (const float*)d_in[8];

  unsigned short* ws = (unsigned short*)d_ws;
  const long SC = 1024L * 512;
  unsigned short* XT  = ws;                        // 3 * 8 * SC (Q,K,V transposed inputs)
  unsigned short* XTV = XT + 16 * SC;
  unsigned short* WQ  = XT + 24 * SC;              // 3 * 512*512 (WQ,WK,WV contiguous)
  unsigned short* WV  = WQ + 2 * 262144;
  unsigned short* QT  = WQ + 3 * 262144;           // 16*SC (Q then K projected)
  unsigned short* KTm = QT + 8 * SC;
  unsigned short* VVm = QT + 16 * SC;              // 8*SC

  transpose_cast3<<<dim3(16, 8, 24), 256, 0, stream>>>(query, key, value, XT);
  cast_w3<<<dim3(256, 3), 256, 0, stream>>>(wq, wk, wv, WQ);
  gemm_qk<<<dim3(4, 8, 16), 256, 0, stream>>>(XT, WQ, QT, bq, bk);
  // V[c,t] = Wv . Xt_v^T + bv (bias over rows)
  gemm_bt<<<dim3(8, 4, 8), 256, 0, stream>>>(WV, XTV, VVm, bv, 512, 1024, 512, 0, SC, SC);
  attn<<<dim3(8, 8, 8), 256, 0, stream>>>(QT, KTm, VVm, (float*)d_out);
}